// Round 2
// baseline (23098.485 us; speedup 1.0000x reference)
//
#include <hip/hip_runtime.h>

typedef unsigned short u16;
typedef unsigned int u32;
typedef __attribute__((ext_vector_type(4))) float f32x4;
typedef __attribute__((ext_vector_type(8))) short bf16x8;
typedef __attribute__((ext_vector_type(4))) u16 u16x4;
typedef __attribute__((ext_vector_type(8))) u16 u16x8;

#define AGENT_SCOPE __HIP_MEMORY_SCOPE_AGENT

__device__ __forceinline__ float loada(const float* p) {
  return __hip_atomic_load((float*)p, __ATOMIC_RELAXED, AGENT_SCOPE);
}
__device__ __forceinline__ void storea(float* p, float v) {
  __hip_atomic_store(p, v, __ATOMIC_RELAXED, AGENT_SCOPE);
}
__device__ __forceinline__ int loadai(const int* p) {
  return __hip_atomic_load((int*)p, __ATOMIC_RELAXED, AGENT_SCOPE);
}
__device__ __forceinline__ void storeai(int* p, int v) {
  __hip_atomic_store(p, v, __ATOMIC_RELAXED, AGENT_SCOPE);
}

__device__ __forceinline__ u16 f2bf(float f) {
  u32 u = __builtin_bit_cast(u32, f);
  u = (u + 0x7FFFu + ((u >> 16) & 1u)) >> 16;
  return (u16)u;
}
__device__ __forceinline__ float b2f(u16 h) {
  return __builtin_bit_cast(float, ((u32)h) << 16);
}
__device__ __forceinline__ float sigf(float x) { return 1.0f / (1.0f + __expf(-x)); }
__device__ __forceinline__ float tanh_(float x) { return 2.0f / (1.0f + __expf(-2.0f * x)) - 1.0f; }

// ---------------------------------------------------------------------------
// fp32 -> bf16 elementwise (vectorized)
// ---------------------------------------------------------------------------
__global__ __launch_bounds__(256) void cvt_bf16_vec(
    const float* __restrict__ in, u16* __restrict__ out, int n4)
{
  int i = blockIdx.x * blockDim.x + threadIdx.x;
  const int stride = gridDim.x * blockDim.x;
  for (; i < n4; i += stride) {
    f32x4 v = ((const f32x4*)in)[i];
    u16x4 o;
    #pragma unroll
    for (int e = 0; e < 4; ++e) o[e] = f2bf(v[e]);
    ((u16x4*)out)[i] = o;
  }
}

// ---------------------------------------------------------------------------
// fp32 (R x C) -> bf16 transposed (C x R)
// ---------------------------------------------------------------------------
__global__ __launch_bounds__(256) void transpose_f32_bf16(
    const float* __restrict__ in, u16* __restrict__ out, int R, int C)
{
  __shared__ float t[32][33];
  const int tx = threadIdx.x & 31, ty = threadIdx.x >> 5; // ty in [0,8)
  const int bx = blockIdx.x * 32, by = blockIdx.y * 32;
  #pragma unroll
  for (int i = 0; i < 4; ++i)
    t[ty + i * 8][tx] = in[(long)(by + ty + i * 8) * C + bx + tx];
  __syncthreads();
  #pragma unroll
  for (int i = 0; i < 4; ++i)
    out[(long)(bx + ty + i * 8) * R + by + tx] = f2bf(t[tx][ty + i * 8]);
}

// ---------------------------------------------------------------------------
// bf16 GEMM: C[M x N] = A[M x K] @ Bt[N x K]^T + bias.
// Output fp32 or bf16 (template). 128x128 tile, BK=64, 4 waves (2x2),
// 16x16x32 MFMA, global_load_lds staging. M%128==0, N%128==0, K%64==0.
// ---------------------------------------------------------------------------
template <bool BF16_OUT>
__global__ __launch_bounds__(256, 2) void gemm_bt(
    const u16* __restrict__ A, const u16* __restrict__ Bt,
    const float* __restrict__ bias, void* __restrict__ Cv,
    int M, int N, int K)
{
  __shared__ u16 As[128 * 64];
  __shared__ u16 Bs[128 * 64];
  const int tid = threadIdx.x;
  const int lane = tid & 63;
  const int wv = tid >> 6;
  const int wm = wv >> 1, wn = wv & 1;
  const long row0 = (long)blockIdx.x * 128;
  const long col0 = (long)blockIdx.y * 128;
  const int lr8 = lane >> 3, lc8 = lane & 7;
  const int fr = lane & 15, fk = (lane >> 4) * 8;
  f32x4 acc[4][4] = {};

  for (int kt = 0; kt < K; kt += 64) {
    __syncthreads();
    #pragma unroll
    for (int ch = 0; ch < 4; ++ch) {
      const int r = wv * 32 + ch * 8;
      const u16* gA = A + (row0 + r + lr8) * (long)K + kt + lc8 * 8;
      __builtin_amdgcn_global_load_lds(
          (const __attribute__((address_space(1))) u32*)gA,
          (__attribute__((address_space(3))) u32*)&As[r * 64], 16, 0, 0);
      const u16* gB = Bt + (col0 + r + lr8) * (long)K + kt + lc8 * 8;
      __builtin_amdgcn_global_load_lds(
          (const __attribute__((address_space(1))) u32*)gB,
          (__attribute__((address_space(3))) u32*)&Bs[r * 64], 16, 0, 0);
    }
    __syncthreads();
    #pragma unroll
    for (int kk = 0; kk < 2; ++kk) {
      bf16x8 af[4], bfv[4];
      #pragma unroll
      for (int m = 0; m < 4; ++m)
        af[m] = *(const bf16x8*)&As[(wm * 64 + m * 16 + fr) * 64 + kk * 32 + fk];
      #pragma unroll
      for (int n = 0; n < 4; ++n)
        bfv[n] = *(const bf16x8*)&Bs[(wn * 64 + n * 16 + fr) * 64 + kk * 32 + fk];
      #pragma unroll
      for (int m = 0; m < 4; ++m)
        #pragma unroll
        for (int n = 0; n < 4; ++n)
          acc[m][n] = __builtin_amdgcn_mfma_f32_16x16x32_bf16(af[m], bfv[n], acc[m][n], 0, 0, 0);
    }
  }

  const int orow = (lane >> 4) * 4, ocol = lane & 15;
  #pragma unroll
  for (int m = 0; m < 4; ++m) {
    #pragma unroll
    for (int n = 0; n < 4; ++n) {
      const long cb = col0 + wn * 64 + n * 16 + ocol;
      const float bv = bias[cb];
      #pragma unroll
      for (int r = 0; r < 4; ++r) {
        const long rr = row0 + wm * 64 + m * 16 + orow + r;
        const float v = acc[m][n][r] + bv;
        if (BF16_OUT) ((u16*)Cv)[rr * (long)N + cb] = f2bf(v);
        else          ((float*)Cv)[rr * (long)N + cb] = v;
      }
    }
  }
}

// ---------------------------------------------------------------------------
// Persistent cooperative scan kernel.
// 256 WGs x 256 threads. 8 groups (group = bid&7), 32 WGs/group,
// 4 batches/group, 16 h-cols per WG.
// Per step: P1 LSTM (MFMA, wave=gate) | P2 k1 | P3 k2+h_new, with a
// flag-array group barrier between phases. Cross-WG state via agent-scope
// relaxed atomics (LLC) => correct regardless of WG->XCD placement.
// ---------------------------------------------------------------------------
#define SS 2048
#define NW 32

__device__ __forceinline__ void gbar(int* gflags, int* myflag, int epoch) {
  __syncthreads();                       // drains all waves' vmem (stores visible)
  __atomic_signal_fence(__ATOMIC_SEQ_CST);
  if (threadIdx.x == 0) storeai(myflag, epoch);
  if (threadIdx.x < NW) {
    while (loadai(gflags + threadIdx.x) < epoch) __builtin_amdgcn_s_sleep(1);
  }
  __atomic_signal_fence(__ATOMIC_SEQ_CST);
  __syncthreads();
}

__device__ __forceinline__ float dot128(const float* hv, const u16* wr, int off) {
  f32x4 a = {0.f, 0.f, 0.f, 0.f};
  #pragma unroll
  for (int kk = 0; kk < 128; kk += 8) {
    u16x8 wb = *(const u16x8*)&wr[off + kk];
    f32x4 h0 = *(const f32x4*)&hv[off + kk];
    f32x4 h1 = *(const f32x4*)&hv[off + kk + 4];
    f32x4 w0, w1;
    #pragma unroll
    for (int e = 0; e < 4; ++e) { w0[e] = b2f(wb[e]); w1[e] = b2f(wb[e + 4]); }
    a = a + h0 * w0;
    a = a + h1 * w1;
  }
  return a[0] + a[1] + a[2] + a[3];
}

__global__ __launch_bounds__(256) void scan_kernel(
    const u16* __restrict__ XZL, const float* __restrict__ XZO,
    const float* __restrict__ TS,
    const u16* __restrict__ WhlT, const u16* __restrict__ WhoT,
    float* H, float* HM, float* U,
    u16* __restrict__ HS,
    float* __restrict__ out_h, float* __restrict__ out_c,
    int* flags)
{
  const int tid = threadIdx.x;
  const int lane = tid & 63;
  const int wv = tid >> 6;
  const int g = blockIdx.x & 7;
  const int w = blockIdx.x >> 3;
  const int j0 = w * 16;

  __shared__ u16 h_bf[2048];        // [4 batches][512] bf16
  __shared__ float vec_l[2048];     // staged h_mem / u, fp32
  __shared__ float z_l[4][4][16];   // [gate][b][jj]
  __shared__ float c_l[4][16];      // LSTM cell state (persistent)

  if (tid < 64) c_l[tid >> 4][tid & 15] = 0.0f;

  // gate-phase mapping (tid < 64)
  const int bg = tid >> 4, jg = tid & 15;
  const long gbg = (long)(g * 4 + bg);
  // phase-2/3 mapping (all 256 threads): (b, j, kquarter)
  const int b23 = tid >> 6, j23 = (tid >> 2) & 15, kq = tid & 3;
  const long gb23 = (long)(g * 4 + b23);
  // phase-1 MFMA lane mapping
  const int bA = (lane & 15) & 3;
  const int kc = (lane >> 4) * 8;
  const long colB = (long)(wv * 512 + j0 + (lane & 15));

  int* const gflags = flags + g * NW;
  int* const myflag = gflags + w;
  int epoch = 0;

  for (int s = 0; s < SS; ++s) {
    // ---- stage h -> h_bf (bf16) ----
    if (s == 0) {
      u16x8 z8 = {0, 0, 0, 0, 0, 0, 0, 0};
      *(u16x8*)&h_bf[tid * 8] = z8;
    } else {
      u16x8 hv;
      #pragma unroll
      for (int i = 0; i < 8; ++i)
        hv[i] = f2bf(loada(&H[g * 2048 + tid * 8 + i]));
      *(u16x8*)&h_bf[tid * 8] = hv;
    }
    // ---- prefetch per-step inputs (hide HBM latency under MFMA) ----
    float zb0 = 0.f, zb1 = 0.f, zb2 = 0.f, zb3 = 0.f;
    if (tid < 64) {
      const u16* p = XZL + (gbg * SS + s) * 2048 + j0 + jg;
      zb0 = b2f(p[0]); zb1 = b2f(p[512]); zb2 = b2f(p[1024]); zb3 = b2f(p[1536]);
    }
    const float zo23 = XZO[(gb23 * SS + s) * 512 + j0 + j23];
    const float tb23 = TS[gb23 * SS + s];
    __syncthreads();

    // ---- phase 1: z_rec = h @ Wh_lstm  (this wave's gate tile = wv) ----
    f32x4 acc = {0.f, 0.f, 0.f, 0.f};
    #pragma unroll 4
    for (int ks = 0; ks < 16; ++ks) {
      bf16x8 af = *(const bf16x8*)&h_bf[bA * 512 + ks * 32 + kc];
      bf16x8 bv = *(const bf16x8*)&WhlT[colB * 512 + ks * 32 + kc];
      acc = __builtin_amdgcn_mfma_f32_16x16x32_bf16(af, bv, acc, 0, 0, 0);
    }
    if (lane < 16) {
      #pragma unroll
      for (int r = 0; r < 4; ++r) z_l[wv][r][lane] = acc[r];
    }
    __syncthreads();

    // ---- gates ----
    if (tid < 64) {
      const float zi = z_l[0][bg][jg] + zb0;
      const float zf = z_l[1][bg][jg] + zb1;
      const float zg = z_l[2][bg][jg] + zb2;
      const float zo = z_l[3][bg][jg] + zb3;
      const float cn = sigf(zf) * c_l[bg][jg] + sigf(zi) * tanh_(zg);
      const float hm = sigf(zo) * tanh_(cn);
      c_l[bg][jg] = cn;
      storea(&HM[gbg * 512 + j0 + jg], hm);
    }
    gbar(gflags, myflag, ++epoch);

    // ---- stage HM -> vec_l ----
    {
      f32x4 v0, v1;
      #pragma unroll
      for (int i = 0; i < 4; ++i) {
        v0[i] = loada(&HM[g * 2048 + tid * 8 + i]);
        v1[i] = loada(&HM[g * 2048 + tid * 8 + 4 + i]);
      }
      *(f32x4*)&vec_l[tid * 8] = v0;
      *(f32x4*)&vec_l[tid * 8 + 4] = v1;
    }
    __syncthreads();

    // ---- phase 2: k1 = tanh(zo + h_mem @ Wh_ode) ----
    float red = dot128(&vec_l[b23 * 512], &WhoT[(long)(j0 + j23) * 512], kq * 128);
    red += __shfl_xor(red, 1);
    red += __shfl_xor(red, 2);
    float k1 = 0.f, hmo = 0.f;
    if (kq == 0) {
      k1 = tanh_(zo23 + red);
      hmo = vec_l[b23 * 512 + j0 + j23];
      storea(&U[gb23 * 512 + j0 + j23], hmo + tb23 * k1);
    }
    gbar(gflags, myflag, ++epoch);

    // ---- stage U -> vec_l ----
    {
      f32x4 v0, v1;
      #pragma unroll
      for (int i = 0; i < 4; ++i) {
        v0[i] = loada(&U[g * 2048 + tid * 8 + i]);
        v1[i] = loada(&U[g * 2048 + tid * 8 + 4 + i]);
      }
      *(f32x4*)&vec_l[tid * 8] = v0;
      *(f32x4*)&vec_l[tid * 8 + 4] = v1;
    }
    __syncthreads();

    // ---- phase 3: k2 = tanh(zo + u @ Wh_ode); h_new ----
    float red2 = dot128(&vec_l[b23 * 512], &WhoT[(long)(j0 + j23) * 512], kq * 128);
    red2 += __shfl_xor(red2, 1);
    red2 += __shfl_xor(red2, 2);
    if (kq == 0) {
      const float k2 = tanh_(zo23 + red2);
      const float hn = hmo + 0.5f * tb23 * (k1 + k2);
      storea(&H[gb23 * 512 + j0 + j23], hn);
      HS[(gb23 * SS + s) * 512 + j0 + j23] = f2bf(hn);
      if (s == SS - 1) out_h[gb23 * 512 + j0 + j23] = hn;
    }
    gbar(gflags, myflag, ++epoch);
  }

  if (tid < 64) out_c[gbg * 512 + j0 + jg] = c_l[bg][jg];
}

// ---------------------------------------------------------------------------
// Host launch
// ---------------------------------------------------------------------------
extern "C" void kernel_launch(void* const* d_in, const int* in_sizes, int n_in,
                              void* d_out, int out_size, void* d_ws, size_t ws_size,
                              hipStream_t stream)
{
  const long B = 32, S = 2048, O = 512;
  const long MS = B * S; // 65536 rows

  const float* x   = (const float*)d_in[0];
  const float* ts  = (const float*)d_in[1];
  const float* Wxl = (const float*)d_in[2];
  const float* Whl = (const float*)d_in[3];
  const float* bl  = (const float*)d_in[4];
  const float* Wxo = (const float*)d_in[5];
  const float* Who = (const float*)d_in[6];
  const float* bo  = (const float*)d_in[7];
  const float* Wfc = (const float*)d_in[8];
  const float* bfc = (const float*)d_in[9];

  float* out = (float*)d_out;
  float* out_h = out + MS * O;          // (B,H) after outputs (B,S,O)
  float* out_c = out_h + B * 512;

  char* ws = (char*)d_ws;
  size_t off = 0;
  auto alloc = [&](size_t bytes) -> void* {
    void* p = ws + off;
    off += (bytes + 255) & ~(size_t)255;
    return p;
  };
  // Workspace layout (~342 MB total):
  u16*   XZL  = (u16*)  alloc(MS * 2048 * 2);   // 268 MB, bf16
  u16*   xb   = (u16*)  alloc(MS * 512 * 2);    // 67 MB; HS aliases this
  u16*   HS   = xb;                             // scan output (after GEMMs read xb)
  u16*   WxlT = (u16*)  alloc(2048 * 512 * 2);
  u16*   WhlT = (u16*)  alloc(2048 * 512 * 2);
  u16*   WxoT = (u16*)  alloc(512 * 512 * 2);
  u16*   WhoT = (u16*)  alloc(512 * 512 * 2);
  u16*   WfcT = (u16*)  alloc(512 * 512 * 2);
  float* Hb   = (float*)alloc(B * 512 * 4);
  float* HM   = (float*)alloc(B * 512 * 4);
  float* Ub   = (float*)alloc(B * 512 * 4);
  int*   flags= (int*)  alloc(4096);

  // XZO (B,S,H) fp32 lives in d_out's outputs region (exactly MS*O floats):
  // written by gemm, fully consumed by the scan, then overwritten by the
  // final output GEMM. Stream-ordered => deterministic under graph replay.
  float* XZO = out;

  if (off > ws_size) return;  // diagnostic: clean absmax failure, not a fault

  hipMemsetAsync(flags, 0, 4096, stream);

  // bf16 conversions / weight transposes
  cvt_bf16_vec<<<2048, 256, 0, stream>>>(x, xb, (int)(MS * 512 / 4));
  transpose_f32_bf16<<<dim3(64, 16), 256, 0, stream>>>(Wxl, WxlT, 512, 2048);
  transpose_f32_bf16<<<dim3(64, 16), 256, 0, stream>>>(Whl, WhlT, 512, 2048);
  transpose_f32_bf16<<<dim3(16, 16), 256, 0, stream>>>(Wxo, WxoT, 512, 512);
  transpose_f32_bf16<<<dim3(16, 16), 256, 0, stream>>>(Who, WhoT, 512, 512);
  transpose_f32_bf16<<<dim3(16, 16), 256, 0, stream>>>(Wfc, WfcT, 512, 512);

  // input-side GEMMs
  gemm_bt<true ><<<dim3(512, 16), 256, 0, stream>>>(xb, WxlT, bl, XZL, (int)MS, 2048, 512);
  gemm_bt<false><<<dim3(512, 4), 256, 0, stream>>>(xb, WxoT, bo, XZO, (int)MS, 512, 512);

  // recurrent scan (cooperative: guarantees 256 co-resident WGs)
  {
    void* args[] = { (void*)&XZL, (void*)&XZO, (void*)&ts, (void*)&WhlT, (void*)&WhoT,
                     (void*)&Hb, (void*)&HM, (void*)&Ub, (void*)&HS,
                     (void*)&out_h, (void*)&out_c, (void*)&flags };
    hipLaunchCooperativeKernel((void*)scan_kernel, dim3(256), dim3(256), args, 0, stream);
  }

  // output GEMM
  gemm_bt<false><<<dim3(512, 4), 256, 0, stream>>>(HS, WfcT, bfc, out, (int)MS, 512, 512);
}